// Round 13
// baseline (149.287 us; speedup 1.0000x reference)
//
#include <hip/hip_runtime.h>
#include <math.h>

constexpr float EPSF = 1e-16f;
#define MAXDEG 64
#define BINCH 4096
#define NBUCK 64

typedef __attribute__((ext_vector_type(8))) short bfrag;   // 8 x bf16
typedef __attribute__((ext_vector_type(4))) float ffrag;   // 4 x f32
typedef __attribute__((ext_vector_type(8))) unsigned short ushortv8;

__device__ __forceinline__ float leaky(float v){ return v >= 0.f ? v : 0.2f*v; }

__device__ __forceinline__ ushort f2bf(float f){
  union { float f; unsigned u; } v; v.f = f;
  unsigned r = (v.u + 0x7FFFu + ((v.u >> 16) & 1u)) >> 16;
  return (ushort)r;
}
__device__ __forceinline__ float bf2f(ushort u){
  union { unsigned u; float f; } v; v.u = ((unsigned)u) << 16;
  return v.f;
}

__device__ __forceinline__ float wred_max(float v){
  #pragma unroll
  for (int d = 32; d; d >>= 1) v = fmaxf(v, __shfl_xor(v, d));
  return v;
}
__device__ __forceinline__ float wred_sum(float v){
  #pragma unroll
  for (int d = 32; d; d >>= 1) v += __shfl_xor(v, d);
  return v;
}

// ---------------- prep: zero ws + W transposes (->bf16) + x->bf16 + p2 = rel . Wsg[257:385] ----------------

__global__ __launch_bounds__(256) void k_prep(const float* __restrict__ Wg, const float* __restrict__ Wlin,
    const float* __restrict__ rel, const float* __restrict__ Wsg, const float* __restrict__ x,
    ushort* __restrict__ Wgt, ushort* __restrict__ Wlt, ushort* __restrict__ xb, float* __restrict__ p2,
    float4* __restrict__ zbase, int znum4, int ZB, int CB, int N){
  __shared__ float tile[32][33];
  int b = blockIdx.x, t = threadIdx.x;
  if (b < ZB){
    int idx = b*256 + t;
    if (idx < znum4) zbase[idx] = make_float4(0.f,0.f,0.f,0.f);
  } else if (b < ZB + 128){
    int bb = b - ZB;
    const float* W = (bb < 64) ? Wg : Wlin;
    ushort* Wt = (bb < 64) ? Wgt : Wlt;
    bb &= 63;
    int bx = (bb & 7)*32, by = (bb >> 3)*32;
    int tx = t & 31, ty = t >> 5;
    for (int r = ty; r < 32; r += 8) tile[r][tx] = W[(size_t)(by+r)*256 + bx+tx];
    __syncthreads();
    for (int r = ty; r < 32; r += 8) Wt[(size_t)(bx+r)*256 + by+tx] = f2bf(tile[tx][r]);
  } else if (b < ZB + 128 + CB){
    // x (fp32) -> xb (bf16), 8 elems/thread
    size_t base = ((size_t)(b - ZB - 128)*256 + t) * 8;
    if (base < (size_t)N*256){
      float4 u0 = *(const float4*)(x + base);
      float4 u1 = *(const float4*)(x + base + 4);
      ushortv8 o;
      o[0] = f2bf(u0.x); o[1] = f2bf(u0.y); o[2] = f2bf(u0.z); o[3] = f2bf(u0.w);
      o[4] = f2bf(u1.x); o[5] = f2bf(u1.y); o[6] = f2bf(u1.z); o[7] = f2bf(u1.w);
      *(ushortv8*)(xb + base) = o;
    }
  } else {
    int node = (b-ZB-128-CB)*4 + (t>>6);
    if (node >= N) return;
    int lane = t & 63;
    const float* rr = rel + (size_t)node*128;
    float q = rr[lane]*Wsg[257+lane] + rr[64+lane]*Wsg[321+lane];
    q = wred_sum(q);
    if (lane == 0) p2[node] = q;
  }
}

// ---------------- fused: GEMM1 (h = xb @ Wg, 128x256 block, + alpha epilogue) || binned edge partition ----------------
// 512 threads. GEMM blocks: 8 waves = 2 row-groups x 4 col-groups, A read once per block.

__global__ __launch_bounds__(512) void k_work1(const ushort* __restrict__ xb, const ushort* __restrict__ Wgt,
    const float* __restrict__ a_src, const float* __restrict__ a_dst,
    ushort* __restrict__ hb, float* __restrict__ as_, float* __restrict__ ad_,
    const int* __restrict__ ei1, const float* __restrict__ et1, const int* __restrict__ ei2,
    int* __restrict__ gcur, int2* __restrict__ bkt1, int2* __restrict__ bkt2,
    int cap1, int cap2, int N, int E1, int E2, int GB1, int B1, int NB){
  __shared__ int hist[NBUCK];
  __shared__ int loff[NBUCK+1];
  __shared__ int cur[NBUCK];
  __shared__ int gbase_s[NBUCK];
  __shared__ int2 stage[BINCH];
  int bid = blockIdx.x, t = threadIdx.x;
  if (bid >= GB1){
    // ---- binning: entries packed as src:15 | ld:9 | bucket:6 ----
    int hop = (bid >= GB1 + B1);
    int cb  = hop ? (bid - GB1 - B1) : (bid - GB1);
    const int* src_arr = hop ? ei2 : ei1;
    const int* dst_arr = hop ? (ei2 + E2) : (ei1 + E1);
    int Eh = hop ? E2 : E1;
    int c0 = cb * BINCH;
    int M = Eh - c0; if (M > BINCH) M = BINCH;
    if (t < NBUCK) hist[t] = 0;
    __syncthreads();
    #pragma unroll
    for (int k = 0; k < BINCH/512; k++){
      int i = k*512 + t;
      if (i < M) atomicAdd(&hist[dst_arr[c0 + i] / NB], 1);
    }
    __syncthreads();
    if (t < NBUCK){
      int v = hist[t];
      int xx = v;
      #pragma unroll
      for (int d = 1; d < NBUCK; d <<= 1){
        int y = __shfl_up(xx, d);
        if (t >= d) xx += y;
      }
      loff[t+1] = xx;
      if (t == 0) loff[0] = 0;
      cur[t] = xx - v;
      gbase_s[t] = atomicAdd(&gcur[hop*NBUCK + t], v);
    }
    __syncthreads();
    #pragma unroll
    for (int k = 0; k < BINCH/512; k++){
      int i = k*512 + t;
      if (i < M){
        int s = src_arr[c0 + i];
        int d = dst_arr[c0 + i];
        int bb = d / NB;
        int ld = d - bb*NB;
        int pos = atomicAdd(&cur[bb], 1);
        float tv = hop ? 0.f : et1[c0 + i];
        stage[pos] = make_int2(s | (ld << 15) | (bb << 24), __float_as_int(tv));
      }
    }
    __syncthreads();
    int2* bkt = hop ? bkt2 : bkt1;
    int cap = hop ? cap2 : cap1;
    for (int s = t; s < M; s += 512){
      int2 en = stage[s];
      int bb = (en.x >> 24) & 63;
      int gpos = gbase_s[bb] + (s - loff[bb]);
      if (gpos < cap) bkt[(size_t)bb*cap + gpos] = en;
    }
    return;
  }
  // ---- gemm h = xb @ Wgt^T, block = 128 rows x 256 cols, 8 waves ----
  int bx = bid;
  int w = t >> 6, lane = t & 63;
  int wr = w >> 2, wc = w & 3;
  int row0 = bx*128 + wr*64;
  int col0 = wc*64;
  int l15 = lane & 15, lk = lane >> 4;
  ffrag acc[4][4];
  #pragma unroll
  for (int i = 0; i < 4; i++)
    #pragma unroll
    for (int j = 0; j < 4; j++){ ffrag z; z[0]=0.f; z[1]=0.f; z[2]=0.f; z[3]=0.f; acc[i][j] = z; }
  for (int kk = 0; kk < 256; kk += 32){
    bfrag a[4], b[4];
    #pragma unroll
    for (int i = 0; i < 4; i++){
      int r = row0 + i*16 + l15; if (r > N-1) r = N-1;
      a[i] = *(const bfrag*)(xb + (size_t)r*256 + kk + lk*8);
      int c = col0 + i*16 + l15;
      b[i] = *(const bfrag*)(Wgt + (size_t)c*256 + kk + lk*8);
    }
    #pragma unroll
    for (int i = 0; i < 4; i++)
      #pragma unroll
      for (int j = 0; j < 4; j++)
        acc[i][j] = __builtin_amdgcn_mfma_f32_16x16x32_bf16(a[i], b[j], acc[i][j], 0, 0, 0);
  }
  float asv[4], adv[4];
  int hd[4];
  #pragma unroll
  for (int j = 0; j < 4; j++){
    int c = col0 + j*16 + l15;
    asv[j] = a_src[c];
    adv[j] = a_dst[c];
    hd[j] = c >> 7;
  }
  #pragma unroll
  for (int i = 0; i < 4; i++){
    float ps[4] = {0.f,0.f,0.f,0.f}, pd[4] = {0.f,0.f,0.f,0.f};
    #pragma unroll
    for (int j = 0; j < 4; j++){
      int c = col0 + j*16 + l15;
      #pragma unroll
      for (int q = 0; q < 4; q++){
        int r = row0 + i*16 + lk*4 + q;
        float v = acc[i][j][q];
        if (r < N) hb[(size_t)r*256 + c] = f2bf(v);
        ps[q] = fmaf(v, asv[j], ps[q]);
        pd[q] = fmaf(v, adv[j], pd[q]);
      }
    }
    int head = hd[0];   // whole wave's 64 cols lie in one head (col0..col0+63, head = col0>>7)
    #pragma unroll
    for (int q = 0; q < 4; q++){
      #pragma unroll
      for (int d = 1; d < 16; d <<= 1){
        ps[q] += __shfl_xor(ps[q], d);
        pd[q] += __shfl_xor(pd[q], d);
      }
      int r = row0 + i*16 + lk*4 + q;
      if (l15 == 0 && r < N){
        // two waves per (r,head) hold partial dots over different column halves: MUST sum
        atomicAdd(&as_[r*2 + head], ps[q]);
        atomicAdd(&ad_[r*2 + head], pd[q]);
      }
    }
  }
}

// ---------------- place: bucket -> padded slot lists (LDS counters, L2-confined writes) ----------------

__global__ __launch_bounds__(256) void k_place(const int* __restrict__ gcur,
    const int2* __restrict__ bkt1, const int2* __restrict__ bkt2, int cap1, int cap2,
    int* __restrict__ ssrc1, int* __restrict__ ssrc2, float* __restrict__ stime1,
    int* __restrict__ cntg, float* __restrict__ ntime, float* __restrict__ p1,
    const float* __restrict__ Wsg, int N, int NB){
  __shared__ int   cnt_l[512];
  __shared__ float ts_l[512];
  int b = blockIdx.x & 63, hop = blockIdx.x >> 6;
  int t = threadIdx.x;
  int nbase = b * NB;
  int ncnt = N - nbase; if (ncnt > NB) ncnt = NB; if (ncnt < 0) ncnt = 0;
  for (int i = t; i < NB; i += 256){ cnt_l[i] = 0; ts_l[i] = 0.f; }
  __syncthreads();
  const int2* bkt = hop ? bkt2 : bkt1;
  int cap = hop ? cap2 : cap1;
  int len = gcur[hop*NBUCK + b]; if (len > cap) len = cap;
  int* ssrc = hop ? ssrc2 : ssrc1;
  for (int i = t; i < len; i += 256){
    int2 en = bkt[(size_t)b*cap + i];
    int src = en.x & 0x7FFF;
    int ld  = (en.x >> 15) & 0x1FF;
    int slot = atomicAdd(&cnt_l[ld], 1);
    if (slot < MAXDEG){
      size_t o = (size_t)(nbase + ld)*MAXDEG + slot;
      ssrc[o] = src;
      if (hop == 0) stime1[o] = __int_as_float(en.y);
    }
    if (hop == 0) atomicAdd(&ts_l[ld], __int_as_float(en.y));
  }
  __syncthreads();
  float w256 = Wsg[256];
  for (int ld = t; ld < ncnt; ld += 256){
    int node = nbase + ld;
    int c = cnt_l[ld];
    cntg[hop*N + node] = c;
    if (hop == 0){
      float nt = ts_l[ld] / ((float)c + EPSF);
      ntime[node] = nt;
      p1[node] = nt * w256;    // init; gemm2 epilogue atomically adds x1 . Wsg[0:256]
    }
  }
}

// ---------------- fused softmax + aggregate, both hops, one wave per node ----------------
// softmax in-register (lane i = edge i); aggregation: lanes 0-31 even edges,
// 32-63 odd edges, 8 ch/lane via 16B loads; 8-edge unroll = 4 gathers in flight/lane.

__global__ __launch_bounds__(256) void k_node(const int* __restrict__ cntg,
    const int* __restrict__ ssrc1, const int* __restrict__ ssrc2,
    const float* __restrict__ as_, const float* __restrict__ ad_,
    const ushort* __restrict__ h, const float* __restrict__ bg,
    ushort* __restrict__ gatb, int N, int gN4){
  __shared__ int   s_src[4][MAXDEG];
  __shared__ float2 s_w[4][MAXDEG];
  int wid = threadIdx.x >> 6, lane = threadIdx.x & 63;
  int hop = blockIdx.x >= gN4;
  int node = (blockIdx.x - (hop ? gN4 : 0))*4 + wid;
  bool active = node < N;
  const int* ssrc = hop ? ssrc2 : ssrc1;
  int deg = 0; float ad0 = 0.f, ad1 = 0.f;
  if (active){
    int degt = cntg[hop*N + node];
    deg = degt > MAXDEG ? MAXDEG : degt;
    ad0 = ad_[node*2]; ad1 = ad_[node*2+1];
  }
  size_t o0 = (size_t)node * MAXDEG;
  // softmax: lane i owns edge i
  int msrc = 0;
  float l0 = -INFINITY, l1 = -INFINITY;
  if (lane < deg){
    msrc = ssrc[o0 + lane];
    float2 a = ((const float2*)as_)[msrc];
    l0 = leaky(a.x + ad0); l1 = leaky(a.y + ad1);
  }
  float m0 = wred_max(l0), m1 = wred_max(l1);
  float x0 = 0.f, x1 = 0.f;
  if (lane < deg){ x0 = __expf(l0 - m0); x1 = __expf(l1 - m1); }
  float e0 = wred_sum(x0), e1 = wred_sum(x1);
  float rd0 = 1.f/(e0 + EPSF), rd1 = 1.f/(e1 + EPSF);
  s_src[wid][lane] = msrc;
  s_w[wid][lane] = make_float2(x0*rd0, x1*rd1);
  // no barrier: each wave reads only its own LDS slice (in-wave ds ordering)
  if (!active) return;
  int eh = lane >> 5, cl = lane & 31, ch0 = cl << 3, head = cl >> 4;
  const int* srow = s_src[wid];
  float acc[8] = {0.f,0.f,0.f,0.f,0.f,0.f,0.f,0.f};
  int i = 0;
  for (; i + 8 <= deg; i += 8){
    int eA = i + eh, eB = i + 2 + eh, eC = i + 4 + eh, eD = i + 6 + eh;
    int sA = srow[eA], sB = srow[eB], sC = srow[eC], sD = srow[eD];
    float2 wA2 = s_w[wid][eA], wB2 = s_w[wid][eB];
    float2 wC2 = s_w[wid][eC], wD2 = s_w[wid][eD];
    float wA = head ? wA2.y : wA2.x;
    float wB = head ? wB2.y : wB2.x;
    float wC = head ? wC2.y : wC2.x;
    float wD = head ? wD2.y : wD2.x;
    ushortv8 uA = *(const ushortv8*)(h + (size_t)sA*256 + ch0);
    ushortv8 uB = *(const ushortv8*)(h + (size_t)sB*256 + ch0);
    ushortv8 uC = *(const ushortv8*)(h + (size_t)sC*256 + ch0);
    ushortv8 uD = *(const ushortv8*)(h + (size_t)sD*256 + ch0);
    #pragma unroll
    for (int k = 0; k < 8; k++) acc[k] = fmaf(wA, bf2f(uA[k]), acc[k]);
    #pragma unroll
    for (int k = 0; k < 8; k++) acc[k] = fmaf(wB, bf2f(uB[k]), acc[k]);
    #pragma unroll
    for (int k = 0; k < 8; k++) acc[k] = fmaf(wC, bf2f(uC[k]), acc[k]);
    #pragma unroll
    for (int k = 0; k < 8; k++) acc[k] = fmaf(wD, bf2f(uD[k]), acc[k]);
  }
  for (; i + 4 <= deg; i += 4){
    int eA = i + eh, eB = i + 2 + eh;
    int sA = srow[eA], sB = srow[eB];
    float2 wA2 = s_w[wid][eA], wB2 = s_w[wid][eB];
    float wA = head ? wA2.y : wA2.x;
    float wB = head ? wB2.y : wB2.x;
    ushortv8 uA = *(const ushortv8*)(h + (size_t)sA*256 + ch0);
    ushortv8 uB = *(const ushortv8*)(h + (size_t)sB*256 + ch0);
    #pragma unroll
    for (int k = 0; k < 8; k++) acc[k] = fmaf(wA, bf2f(uA[k]), acc[k]);
    #pragma unroll
    for (int k = 0; k < 8; k++) acc[k] = fmaf(wB, bf2f(uB[k]), acc[k]);
  }
  for (; i < deg; i += 2){
    int e = i + eh;
    bool v = e < deg;
    int s = v ? srow[e] : 0;
    float w = 0.f;
    if (v){ float2 w2 = s_w[wid][e]; w = head ? w2.y : w2.x; }
    ushortv8 u = *(const ushortv8*)(h + (size_t)s*256 + ch0);
    #pragma unroll
    for (int k = 0; k < 8; k++) acc[k] = fmaf(w, bf2f(u[k]), acc[k]);
  }
  #pragma unroll
  for (int k = 0; k < 8; k++) acc[k] += __shfl_xor(acc[k], 32);
  if (eh == 0){
    float4 b0 = *(const float4*)(bg + ch0);
    float4 b1 = *(const float4*)(bg + ch0 + 4);
    ushortv8 o;
    o[0] = f2bf(acc[0] + b0.x); o[1] = f2bf(acc[1] + b0.y);
    o[2] = f2bf(acc[2] + b0.z); o[3] = f2bf(acc[3] + b0.w);
    o[4] = f2bf(acc[4] + b1.x); o[5] = f2bf(acc[5] + b1.y);
    o[6] = f2bf(acc[6] + b1.z); o[7] = f2bf(acc[7] + b1.w);
    *(ushortv8*)(gatb + (size_t)(hop ? N + node : node)*256 + ch0) = o;
  }
}

// ---------------- GEMM2: x12 = [gat1;gat2] @ Wlin + blin (bf16 out, 128x256 block) + p1 epilogue ----------------

__global__ __launch_bounds__(512) void k_gemm2(const ushort* __restrict__ A, const ushort* __restrict__ Bt,
    const float* __restrict__ bias, const float* __restrict__ Wsg,
    ushort* __restrict__ Cb, float* __restrict__ p1, int M, int N){
  int t = threadIdx.x;
  int w = t >> 6, lane = t & 63;
  int wr = w >> 2, wc = w & 3;
  int row0 = blockIdx.x*128 + wr*64;
  int col0 = wc*64;
  int l15 = lane & 15, lk = lane >> 4;
  ffrag acc[4][4];
  #pragma unroll
  for (int i = 0; i < 4; i++)
    #pragma unroll
    for (int j = 0; j < 4; j++){ ffrag z; z[0]=0.f; z[1]=0.f; z[2]=0.f; z[3]=0.f; acc[i][j] = z; }
  for (int kk = 0; kk < 256; kk += 32){
    bfrag a[4], b[4];
    #pragma unroll
    for (int i = 0; i < 4; i++){
      int r = row0 + i*16 + l15; if (r > M-1) r = M-1;
      a[i] = *(const bfrag*)(A + (size_t)r*256 + kk + lk*8);
      int c = col0 + i*16 + l15;
      b[i] = *(const bfrag*)(Bt + (size_t)c*256 + kk + lk*8);
    }
    #pragma unroll
    for (int i = 0; i < 4; i++)
      #pragma unroll
      for (int j = 0; j < 4; j++)
        acc[i][j] = __builtin_amdgcn_mfma_f32_16x16x32_bf16(a[i], b[j], acc[i][j], 0, 0, 0);
  }
  float wsv[4]; float bv[4];
  #pragma unroll
  for (int j = 0; j < 4; j++){
    int c = col0 + j*16 + l15;
    wsv[j] = Wsg[c];
    bv[j] = bias[c];
  }
  #pragma unroll
  for (int i = 0; i < 4; i++){
    float ps[4] = {0.f,0.f,0.f,0.f};
    #pragma unroll
    for (int j = 0; j < 4; j++){
      int c = col0 + j*16 + l15;
      #pragma unroll
      for (int q = 0; q < 4; q++){
        int r = row0 + i*16 + lk*4 + q;
        float v = acc[i][j][q] + bv[j];
        if (r < M) Cb[(size_t)r*256 + c] = f2bf(v);
        ps[q] = fmaf(v, wsv[j], ps[q]);
      }
    }
    #pragma unroll
    for (int q = 0; q < 4; q++){
      #pragma unroll
      for (int d = 1; d < 16; d <<= 1) ps[q] += __shfl_xor(ps[q], d);
      int r = row0 + i*16 + lk*4 + q;
      if (l15 == 0 && r < N) atomicAdd(&p1[r], ps[q]);
    }
  }
}

// ---------------- final: fused semantic sigmoid-mean + gate + mix, one wave per node ----------------

__global__ __launch_bounds__(256) void k_final(const ushort* __restrict__ x1, const ushort* __restrict__ x2r,
    const int* __restrict__ cntg, const int* __restrict__ ssrc1, const float* __restrict__ stime1,
    const float* __restrict__ p1, const float* __restrict__ p2,
    const float* __restrict__ Wsg, const float* __restrict__ bsg,
    const float* __restrict__ ntime, const float* __restrict__ Wtg, const float* __restrict__ btg,
    float* __restrict__ out, int N){
  int node = blockIdx.x*4 + (threadIdx.x>>6);
  if (node >= N) return;
  int lane = threadIdx.x & 63;
  int degt = cntg[node];
  int deg = degt > MAXDEG ? MAXDEG : degt;
  float acc = 0.f;
  if (lane < deg){
    size_t o = (size_t)node*MAXDEG + lane;
    float z = p1[ssrc1[o]] + p2[node] + bsg[0] + stime1[o]*Wsg[385];
    acc = 1.f / (1.f + __expf(-z));
  }
  acc = wred_sum(acc);
  float sm = acc / ((float)degt + EPSF);
  float nt = ntime[node];
  int c0 = lane << 2;
  ushort4 au = *(const ushort4*)(x1  + (size_t)node*256 + c0);
  ushort4 ru = *(const ushort4*)(x2r + (size_t)node*256 + c0);
  float4 a4 = make_float4(bf2f(au.x), bf2f(au.y), bf2f(au.z), bf2f(au.w));
  float4 b4; b4.x = bf2f(ru.x)*sm; b4.y = bf2f(ru.y)*sm; b4.z = bf2f(ru.z)*sm; b4.w = bf2f(ru.w)*sm;
  float4 w1 = *(const float4*)(Wtg + c0);
  float4 w2 = *(const float4*)(Wtg + 257 + c0);
  float s = a4.x*w1.x + a4.y*w1.y + a4.z*w1.z + a4.w*w1.w
          + b4.x*w2.x + b4.y*w2.y + b4.z*w2.z + b4.w*w2.w;
  if (lane == 0) s += nt*Wtg[256] + nt*Wtg[513] + btg[0];
  s = wred_sum(s);
  float g = 1.f / (1.f + __expf(-s));
  float* orow = out + (size_t)node*257;
  orow[c0+0] = g*b4.x + (1.f - g)*a4.x;
  orow[c0+1] = g*b4.y + (1.f - g)*a4.y;
  orow[c0+2] = g*b4.z + (1.f - g)*a4.z;
  orow[c0+3] = g*b4.w + (1.f - g)*a4.w;
  if (lane == 0) orow[256] = nt;
}

// ---------------- launch ----------------

extern "C" void kernel_launch(void* const* d_in, const int* in_sizes, int n_in,
                              void* d_out, int out_size, void* d_ws, size_t ws_size,
                              hipStream_t stream){
  const float* x    = (const float*)d_in[0];
  const int*   ei1  = (const int*)d_in[1];
  const float* et1  = (const float*)d_in[2];
  const int*   ei2  = (const int*)d_in[3];
  const float* rel  = (const float*)d_in[5];
  const float* Wg   = (const float*)d_in[6];
  const float* asrc = (const float*)d_in[7];
  const float* adst = (const float*)d_in[8];
  const float* bg   = (const float*)d_in[9];
  const float* Wlin = (const float*)d_in[10];
  const float* blin = (const float*)d_in[11];
  const float* Wtg  = (const float*)d_in[12];
  const float* btg  = (const float*)d_in[13];
  const float* Wsg  = (const float*)d_in[14];
  const float* bsg  = (const float*)d_in[15];
  float* out = (float*)d_out;

  const int N  = in_sizes[0] / 256;
  const int E1 = in_sizes[1] / 2;
  const int E2 = in_sizes[3] / 2;
  const int NB = (N + NBUCK - 1) / NBUCK;
  const int cap1 = E1/NBUCK + 2048;
  const int cap2 = E2/NBUCK + 2048;

  char* base = (char*)d_ws;
  size_t off = 0;
  auto alloc = [&](size_t bytes)->char*{
    char* p = base + off;
    off += (bytes + 255) & ~(size_t)255;
    return p;
  };
  // zeroed region (cleared by k_prep): gcur | as_ | ad_ (accumulated via atomicAdd)
  int*    gcur  = (int*)alloc((size_t)2*NBUCK*4);
  float*  as_   = (float*)alloc((size_t)2*N*4);
  float*  ad_   = (float*)alloc((size_t)2*N*4);
  size_t zero_bytes = off;
  ushort* Wgt   = (ushort*)alloc((size_t)256*256*2);
  ushort* Wlt   = (ushort*)alloc((size_t)256*256*2);
  ushort* xb    = (ushort*)alloc((size_t)N*256*2);
  ushort* hb    = (ushort*)alloc((size_t)N*256*2);
  ushort* gatb  = (ushort*)alloc((size_t)2*N*256*2);
  ushort* x12   = (ushort*)alloc((size_t)2*N*256*2);
  float*  ntime = (float*)alloc((size_t)N*4);
  float*  p1    = (float*)alloc((size_t)N*4);
  float*  p2    = (float*)alloc((size_t)N*4);
  int*    cntg  = (int*)alloc((size_t)2*N*4);
  int*    ssrc1 = (int*)alloc((size_t)N*MAXDEG*4);
  int*    ssrc2 = (int*)alloc((size_t)N*MAXDEG*4);
  float*  stime1= (float*)alloc((size_t)N*MAXDEG*4);
  int2*   bkt1  = (int2*)alloc((size_t)NBUCK*cap1*8);
  int2*   bkt2  = (int2*)alloc((size_t)NBUCK*cap2*8);

  dim3 blk(256);
  int gN4 = (N + 3) / 4;
  int GB1 = (N + 127) / 128;
  int B1  = (E1 + BINCH - 1) / BINCH;
  int B2  = (E2 + BINCH - 1) / BINCH;
  int znum4 = (int)(zero_bytes / 16);
  int ZB = (znum4 + 255) / 256;
  int CB = (N*256/8 + 255) / 256;
  int gG2 = (2*N + 127) / 128;

  k_prep<<<ZB + 128 + CB + gN4, blk, 0, stream>>>(Wg, Wlin, rel, Wsg, x, Wgt, Wlt, xb, p2,
                                                  (float4*)d_ws, znum4, ZB, CB, N);
  k_work1<<<GB1 + B1 + B2, dim3(512), 0, stream>>>(xb, Wgt, asrc, adst, hb, as_, ad_,
                                                   ei1, et1, ei2, gcur, bkt1, bkt2,
                                                   cap1, cap2, N, E1, E2, GB1, B1, NB);
  k_place<<<128, blk, 0, stream>>>(gcur, bkt1, bkt2, cap1, cap2, ssrc1, ssrc2, stime1,
                                   cntg, ntime, p1, Wsg, N, NB);
  k_node<<<2*gN4, blk, 0, stream>>>(cntg, ssrc1, ssrc2, as_, ad_, hb, bg, gatb, N, gN4);
  k_gemm2<<<gG2, dim3(512), 0, stream>>>(gatb, Wlt, blin, Wsg, x12, p1, 2*N, N);
  k_final<<<gN4, blk, 0, stream>>>(x12, x12 + (size_t)N*256, cntg, ssrc1, stime1,
                                   p1, p2, Wsg, bsg, ntime, Wtg, btg, out, N);
}

// Round 14
// 147.946 us; speedup vs baseline: 1.0091x; 1.0091x over previous
//
#include <hip/hip_runtime.h>
#include <math.h>

constexpr float EPSF = 1e-16f;
#define MAXDEG 64
#define BINCH 4096
#define NBUCK 64

typedef __attribute__((ext_vector_type(8))) short bfrag;   // 8 x bf16
typedef __attribute__((ext_vector_type(4))) float ffrag;   // 4 x f32
typedef __attribute__((ext_vector_type(8))) unsigned short ushortv8;

__device__ __forceinline__ float leaky(float v){ return v >= 0.f ? v : 0.2f*v; }

__device__ __forceinline__ ushort f2bf(float f){
  union { float f; unsigned u; } v; v.f = f;
  unsigned r = (v.u + 0x7FFFu + ((v.u >> 16) & 1u)) >> 16;
  return (ushort)r;
}
__device__ __forceinline__ float bf2f(ushort u){
  union { unsigned u; float f; } v; v.u = ((unsigned)u) << 16;
  return v.f;
}

__device__ __forceinline__ float wred_max(float v){
  #pragma unroll
  for (int d = 32; d; d >>= 1) v = fmaxf(v, __shfl_xor(v, d));
  return v;
}
__device__ __forceinline__ float wred_sum(float v){
  #pragma unroll
  for (int d = 32; d; d >>= 1) v += __shfl_xor(v, d);
  return v;
}

// ---------------- prep: zero ws + W transposes (->bf16) + x->bf16 + p2 = rel . Wsg[257:385] ----------------

__global__ __launch_bounds__(256) void k_prep(const float* __restrict__ Wg, const float* __restrict__ Wlin,
    const float* __restrict__ rel, const float* __restrict__ Wsg, const float* __restrict__ x,
    ushort* __restrict__ Wgt, ushort* __restrict__ Wlt, ushort* __restrict__ xb, float* __restrict__ p2,
    float4* __restrict__ zbase, int znum4, int ZB, int CB, int N){
  __shared__ float tile[32][33];
  int b = blockIdx.x, t = threadIdx.x;
  if (b < ZB){
    int idx = b*256 + t;
    if (idx < znum4) zbase[idx] = make_float4(0.f,0.f,0.f,0.f);
  } else if (b < ZB + 128){
    int bb = b - ZB;
    const float* W = (bb < 64) ? Wg : Wlin;
    ushort* Wt = (bb < 64) ? Wgt : Wlt;
    bb &= 63;
    int bx = (bb & 7)*32, by = (bb >> 3)*32;
    int tx = t & 31, ty = t >> 5;
    for (int r = ty; r < 32; r += 8) tile[r][tx] = W[(size_t)(by+r)*256 + bx+tx];
    __syncthreads();
    for (int r = ty; r < 32; r += 8) Wt[(size_t)(bx+r)*256 + by+tx] = f2bf(tile[tx][r]);
  } else if (b < ZB + 128 + CB){
    // x (fp32) -> xb (bf16), 8 elems/thread
    size_t base = ((size_t)(b - ZB - 128)*256 + t) * 8;
    if (base < (size_t)N*256){
      float4 u0 = *(const float4*)(x + base);
      float4 u1 = *(const float4*)(x + base + 4);
      ushortv8 o;
      o[0] = f2bf(u0.x); o[1] = f2bf(u0.y); o[2] = f2bf(u0.z); o[3] = f2bf(u0.w);
      o[4] = f2bf(u1.x); o[5] = f2bf(u1.y); o[6] = f2bf(u1.z); o[7] = f2bf(u1.w);
      *(ushortv8*)(xb + base) = o;
    }
  } else {
    int node = (b-ZB-128-CB)*4 + (t>>6);
    if (node >= N) return;
    int lane = t & 63;
    const float* rr = rel + (size_t)node*128;
    float q = rr[lane]*Wsg[257+lane] + rr[64+lane]*Wsg[321+lane];
    q = wred_sum(q);
    if (lane == 0) p2[node] = q;
  }
}

// ---------------- fused: GEMM1 (h = xb @ Wg + alpha epilogue) || binned edge partition ----------------

__global__ __launch_bounds__(256) void k_work1(const ushort* __restrict__ xb, const ushort* __restrict__ Wgt,
    const float* __restrict__ a_src, const float* __restrict__ a_dst,
    ushort* __restrict__ hb, float* __restrict__ as_, float* __restrict__ ad_,
    const int* __restrict__ ei1, const float* __restrict__ et1, const int* __restrict__ ei2,
    int* __restrict__ gcur, int2* __restrict__ bkt1, int2* __restrict__ bkt2,
    int cap1, int cap2, int N, int E1, int E2, int GB1, int B1, int NB){
  __shared__ int hist[NBUCK];
  __shared__ int loff[NBUCK+1];
  __shared__ int cur[NBUCK];
  __shared__ int gbase_s[NBUCK];
  __shared__ int2 stage[BINCH];
  int bid = blockIdx.x, t = threadIdx.x;
  if (bid >= GB1){
    // ---- binning ----
    int hop = (bid >= GB1 + B1);
    int cb  = hop ? (bid - GB1 - B1) : (bid - GB1);
    const int* src_arr = hop ? ei2 : ei1;
    const int* dst_arr = hop ? (ei2 + E2) : (ei1 + E1);
    int Eh = hop ? E2 : E1;
    int c0 = cb * BINCH;
    int M = Eh - c0; if (M > BINCH) M = BINCH;
    if (t < NBUCK) hist[t] = 0;
    __syncthreads();
    #pragma unroll
    for (int k = 0; k < BINCH/256; k++){
      int i = k*256 + t;
      if (i < M) atomicAdd(&hist[dst_arr[c0 + i] / NB], 1);
    }
    __syncthreads();
    if (t < NBUCK){
      int v = hist[t];
      int xx = v;
      #pragma unroll
      for (int d = 1; d < NBUCK; d <<= 1){
        int y = __shfl_up(xx, d);
        if (t >= d) xx += y;
      }
      loff[t+1] = xx;
      if (t == 0) loff[0] = 0;
      cur[t] = xx - v;
      gbase_s[t] = atomicAdd(&gcur[hop*NBUCK + t], v);
    }
    __syncthreads();
    #pragma unroll
    for (int k = 0; k < BINCH/256; k++){
      int i = k*256 + t;
      if (i < M){
        int s = src_arr[c0 + i];
        int d = dst_arr[c0 + i];
        int bb = d / NB;
        int ld = d - bb*NB;
        int pos = atomicAdd(&cur[bb], 1);
        float tv = hop ? 0.f : et1[c0 + i];
        stage[pos] = make_int2(s | (ld << 15), __float_as_int(tv));
      }
    }
    __syncthreads();
    int2* bkt = hop ? bkt2 : bkt1;
    int cap = hop ? cap2 : cap1;
    for (int s = t; s < M; s += 256){
      int lo = 0, hi = NBUCK;
      while (hi - lo > 1){ int mid = (lo + hi) >> 1; if (loff[mid] <= s) lo = mid; else hi = mid; }
      int gpos = gbase_s[lo] + (s - loff[lo]);
      if (gpos < cap) bkt[(size_t)lo*cap + gpos] = stage[s];
    }
    return;
  }
  // ---- gemm h = xb @ Wgt^T (bf16 A direct loads), 128x128 tile, + alpha epilogue ----
  int head = bid & 1;
  int bx = bid >> 1;
  int wid = t >> 6, lane = t & 63;
  int wr = wid >> 1, wc = wid & 1;
  int row0 = bx*128 + wr*64;
  int col0 = head*128 + wc*64;
  int l15 = lane & 15, lk = lane >> 4;
  ffrag acc[4][4];
  #pragma unroll
  for (int i = 0; i < 4; i++)
    #pragma unroll
    for (int j = 0; j < 4; j++){ ffrag z; z[0]=0.f; z[1]=0.f; z[2]=0.f; z[3]=0.f; acc[i][j] = z; }
  for (int kk = 0; kk < 256; kk += 32){
    bfrag a[4], b[4];
    #pragma unroll
    for (int i = 0; i < 4; i++){
      int r = row0 + i*16 + l15; if (r > N-1) r = N-1;
      a[i] = *(const bfrag*)(xb + (size_t)r*256 + kk + lk*8);
      int c = col0 + i*16 + l15;
      b[i] = *(const bfrag*)(Wgt + (size_t)c*256 + kk + lk*8);
    }
    #pragma unroll
    for (int i = 0; i < 4; i++)
      #pragma unroll
      for (int j = 0; j < 4; j++)
        acc[i][j] = __builtin_amdgcn_mfma_f32_16x16x32_bf16(a[i], b[j], acc[i][j], 0, 0, 0);
  }
  float asv[4], adv[4];
  #pragma unroll
  for (int j = 0; j < 4; j++){
    int cc = wc*64 + j*16 + l15;
    asv[j] = a_src[head*128 + cc];
    adv[j] = a_dst[head*128 + cc];
  }
  #pragma unroll
  for (int i = 0; i < 4; i++){
    float ps[4] = {0.f,0.f,0.f,0.f}, pd[4] = {0.f,0.f,0.f,0.f};
    #pragma unroll
    for (int j = 0; j < 4; j++){
      int c = col0 + j*16 + l15;
      #pragma unroll
      for (int q = 0; q < 4; q++){
        int r = row0 + i*16 + lk*4 + q;
        float v = acc[i][j][q];
        if (r < N) hb[(size_t)r*256 + c] = f2bf(v);
        ps[q] = fmaf(v, asv[j], ps[q]);
        pd[q] = fmaf(v, adv[j], pd[q]);
      }
    }
    #pragma unroll
    for (int q = 0; q < 4; q++){
      #pragma unroll
      for (int d = 1; d < 16; d <<= 1){
        ps[q] += __shfl_xor(ps[q], d);
        pd[q] += __shfl_xor(pd[q], d);
      }
      int r = row0 + i*16 + lk*4 + q;
      if (l15 == 0 && r < N){
        // two waves (wc=0/1) hold partial dots over different column halves: MUST sum
        atomicAdd(&as_[r*2 + head], ps[q]);
        atomicAdd(&ad_[r*2 + head], pd[q]);
      }
    }
  }
}

// ---------------- place: bucket -> padded slot lists (LDS counters, L2-confined writes) ----------------

__global__ __launch_bounds__(256) void k_place(const int* __restrict__ gcur,
    const int2* __restrict__ bkt1, const int2* __restrict__ bkt2, int cap1, int cap2,
    int* __restrict__ ssrc1, int* __restrict__ ssrc2, float* __restrict__ stime1,
    int* __restrict__ cntg, float* __restrict__ ntime, float* __restrict__ p1,
    const float* __restrict__ Wsg, int N, int NB){
  __shared__ int   cnt_l[512];
  __shared__ float ts_l[512];
  int b = blockIdx.x & 63, hop = blockIdx.x >> 6;
  int t = threadIdx.x;
  int nbase = b * NB;
  int ncnt = N - nbase; if (ncnt > NB) ncnt = NB; if (ncnt < 0) ncnt = 0;
  for (int i = t; i < NB; i += 256){ cnt_l[i] = 0; ts_l[i] = 0.f; }
  __syncthreads();
  const int2* bkt = hop ? bkt2 : bkt1;
  int cap = hop ? cap2 : cap1;
  int len = gcur[hop*NBUCK + b]; if (len > cap) len = cap;
  int* ssrc = hop ? ssrc2 : ssrc1;
  for (int i = t; i < len; i += 256){
    int2 en = bkt[(size_t)b*cap + i];
    int src = en.x & 0x7FFF;
    int ld  = en.x >> 15;
    int slot = atomicAdd(&cnt_l[ld], 1);
    if (slot < MAXDEG){
      size_t o = (size_t)(nbase + ld)*MAXDEG + slot;
      ssrc[o] = src;
      if (hop == 0) stime1[o] = __int_as_float(en.y);
    }
    if (hop == 0) atomicAdd(&ts_l[ld], __int_as_float(en.y));
  }
  __syncthreads();
  float w256 = Wsg[256];
  for (int ld = t; ld < ncnt; ld += 256){
    int node = nbase + ld;
    int c = cnt_l[ld];
    cntg[hop*N + node] = c;
    if (hop == 0){
      float nt = ts_l[ld] / ((float)c + EPSF);
      ntime[node] = nt;
      p1[node] = nt * w256;    // init; gemm2 epilogue atomically adds x1 . Wsg[0:256]
    }
  }
}

// ---------------- fused softmax + aggregate, both hops, one wave per node ----------------
// softmax in-register (lane i = edge i); aggregation: lanes 0-31 even edges,
// 32-63 odd edges, 8 ch/lane via 16B loads; 8-edge unroll = 4 gathers in flight/lane.

__global__ __launch_bounds__(256) void k_node(const int* __restrict__ cntg,
    const int* __restrict__ ssrc1, const int* __restrict__ ssrc2,
    const float* __restrict__ as_, const float* __restrict__ ad_,
    const ushort* __restrict__ h, const float* __restrict__ bg,
    ushort* __restrict__ gatb, int N, int gN4){
  __shared__ int   s_src[4][MAXDEG];
  __shared__ float2 s_w[4][MAXDEG];
  int wid = threadIdx.x >> 6, lane = threadIdx.x & 63;
  int hop = blockIdx.x >= gN4;
  int node = (blockIdx.x - (hop ? gN4 : 0))*4 + wid;
  bool active = node < N;
  const int* ssrc = hop ? ssrc2 : ssrc1;
  int deg = 0; float ad0 = 0.f, ad1 = 0.f;
  if (active){
    int degt = cntg[hop*N + node];
    deg = degt > MAXDEG ? MAXDEG : degt;
    ad0 = ad_[node*2]; ad1 = ad_[node*2+1];
  }
  size_t o0 = (size_t)node * MAXDEG;
  // softmax: lane i owns edge i
  int msrc = 0;
  float l0 = -INFINITY, l1 = -INFINITY;
  if (lane < deg){
    msrc = ssrc[o0 + lane];
    float2 a = ((const float2*)as_)[msrc];
    l0 = leaky(a.x + ad0); l1 = leaky(a.y + ad1);
  }
  float m0 = wred_max(l0), m1 = wred_max(l1);
  float x0 = 0.f, x1 = 0.f;
  if (lane < deg){ x0 = __expf(l0 - m0); x1 = __expf(l1 - m1); }
  float e0 = wred_sum(x0), e1 = wred_sum(x1);
  float rd0 = 1.f/(e0 + EPSF), rd1 = 1.f/(e1 + EPSF);
  s_src[wid][lane] = msrc;
  s_w[wid][lane] = make_float2(x0*rd0, x1*rd1);
  // no barrier: each wave reads only its own LDS slice (in-wave ds ordering)
  if (!active) return;
  int eh = lane >> 5, cl = lane & 31, ch0 = cl << 3, head = cl >> 4;
  const int* srow = s_src[wid];
  float acc[8] = {0.f,0.f,0.f,0.f,0.f,0.f,0.f,0.f};
  int i = 0;
  for (; i + 8 <= deg; i += 8){
    int eA = i + eh, eB = i + 2 + eh, eC = i + 4 + eh, eD = i + 6 + eh;
    int sA = srow[eA], sB = srow[eB], sC = srow[eC], sD = srow[eD];
    float2 wA2 = s_w[wid][eA], wB2 = s_w[wid][eB];
    float2 wC2 = s_w[wid][eC], wD2 = s_w[wid][eD];
    float wA = head ? wA2.y : wA2.x;
    float wB = head ? wB2.y : wB2.x;
    float wC = head ? wC2.y : wC2.x;
    float wD = head ? wD2.y : wD2.x;
    ushortv8 uA = *(const ushortv8*)(h + (size_t)sA*256 + ch0);
    ushortv8 uB = *(const ushortv8*)(h + (size_t)sB*256 + ch0);
    ushortv8 uC = *(const ushortv8*)(h + (size_t)sC*256 + ch0);
    ushortv8 uD = *(const ushortv8*)(h + (size_t)sD*256 + ch0);
    #pragma unroll
    for (int k = 0; k < 8; k++) acc[k] = fmaf(wA, bf2f(uA[k]), acc[k]);
    #pragma unroll
    for (int k = 0; k < 8; k++) acc[k] = fmaf(wB, bf2f(uB[k]), acc[k]);
    #pragma unroll
    for (int k = 0; k < 8; k++) acc[k] = fmaf(wC, bf2f(uC[k]), acc[k]);
    #pragma unroll
    for (int k = 0; k < 8; k++) acc[k] = fmaf(wD, bf2f(uD[k]), acc[k]);
  }
  for (; i + 4 <= deg; i += 4){
    int eA = i + eh, eB = i + 2 + eh;
    int sA = srow[eA], sB = srow[eB];
    float2 wA2 = s_w[wid][eA], wB2 = s_w[wid][eB];
    float wA = head ? wA2.y : wA2.x;
    float wB = head ? wB2.y : wB2.x;
    ushortv8 uA = *(const ushortv8*)(h + (size_t)sA*256 + ch0);
    ushortv8 uB = *(const ushortv8*)(h + (size_t)sB*256 + ch0);
    #pragma unroll
    for (int k = 0; k < 8; k++) acc[k] = fmaf(wA, bf2f(uA[k]), acc[k]);
    #pragma unroll
    for (int k = 0; k < 8; k++) acc[k] = fmaf(wB, bf2f(uB[k]), acc[k]);
  }
  for (; i < deg; i += 2){
    int e = i + eh;
    bool v = e < deg;
    int s = v ? srow[e] : 0;
    float w = 0.f;
    if (v){ float2 w2 = s_w[wid][e]; w = head ? w2.y : w2.x; }
    ushortv8 u = *(const ushortv8*)(h + (size_t)s*256 + ch0);
    #pragma unroll
    for (int k = 0; k < 8; k++) acc[k] = fmaf(w, bf2f(u[k]), acc[k]);
  }
  #pragma unroll
  for (int k = 0; k < 8; k++) acc[k] += __shfl_xor(acc[k], 32);
  if (eh == 0){
    float4 b0 = *(const float4*)(bg + ch0);
    float4 b1 = *(const float4*)(bg + ch0 + 4);
    ushortv8 o;
    o[0] = f2bf(acc[0] + b0.x); o[1] = f2bf(acc[1] + b0.y);
    o[2] = f2bf(acc[2] + b0.z); o[3] = f2bf(acc[3] + b0.w);
    o[4] = f2bf(acc[4] + b1.x); o[5] = f2bf(acc[5] + b1.y);
    o[6] = f2bf(acc[6] + b1.z); o[7] = f2bf(acc[7] + b1.w);
    *(ushortv8*)(gatb + (size_t)(hop ? N + node : node)*256 + ch0) = o;
  }
}

// ---------------- GEMM2: x12 = [gat1;gat2] @ Wlin + blin (bf16 out) + p1 epilogue for rows<N ----------------

__global__ __launch_bounds__(256) void k_gemm2(const ushort* __restrict__ A, const ushort* __restrict__ Bt,
    const float* __restrict__ bias, const float* __restrict__ Wsg,
    ushort* __restrict__ Cb, float* __restrict__ p1, int M, int N){
  int wid = threadIdx.x >> 6, lane = threadIdx.x & 63;
  int wr = wid >> 1, wc = wid & 1;
  int row0 = blockIdx.x*128 + wr*64;
  int col0 = blockIdx.y*128 + wc*64;
  int l15 = lane & 15, lk = lane >> 4;
  ffrag acc[4][4];
  #pragma unroll
  for (int i = 0; i < 4; i++)
    #pragma unroll
    for (int j = 0; j < 4; j++){ ffrag z; z[0]=0.f; z[1]=0.f; z[2]=0.f; z[3]=0.f; acc[i][j] = z; }
  for (int kk = 0; kk < 256; kk += 32){
    bfrag a[4], b[4];
    #pragma unroll
    for (int i = 0; i < 4; i++){
      int r = row0 + i*16 + l15; if (r > M-1) r = M-1;
      a[i] = *(const bfrag*)(A + (size_t)r*256 + kk + lk*8);
      int c = col0 + i*16 + l15;
      b[i] = *(const bfrag*)(Bt + (size_t)c*256 + kk + lk*8);
    }
    #pragma unroll
    for (int i = 0; i < 4; i++)
      #pragma unroll
      for (int j = 0; j < 4; j++)
        acc[i][j] = __builtin_amdgcn_mfma_f32_16x16x32_bf16(a[i], b[j], acc[i][j], 0, 0, 0);
  }
  float wsv[4]; float bv[4];
  #pragma unroll
  for (int j = 0; j < 4; j++){
    int c = col0 + j*16 + l15;
    wsv[j] = Wsg[c];
    bv[j] = bias[c];
  }
  #pragma unroll
  for (int i = 0; i < 4; i++){
    float ps[4] = {0.f,0.f,0.f,0.f};
    #pragma unroll
    for (int j = 0; j < 4; j++){
      int c = col0 + j*16 + l15;
      #pragma unroll
      for (int q = 0; q < 4; q++){
        int r = row0 + i*16 + lk*4 + q;
        float v = acc[i][j][q] + bv[j];
        if (r < M) Cb[(size_t)r*256 + c] = f2bf(v);
        ps[q] = fmaf(v, wsv[j], ps[q]);
      }
    }
    #pragma unroll
    for (int q = 0; q < 4; q++){
      #pragma unroll
      for (int d = 1; d < 16; d <<= 1) ps[q] += __shfl_xor(ps[q], d);
      int r = row0 + i*16 + lk*4 + q;
      if (l15 == 0 && r < N) atomicAdd(&p1[r], ps[q]);
    }
  }
}

// ---------------- final: fused semantic sigmoid-mean + gate + mix, one wave per node ----------------

__global__ __launch_bounds__(256) void k_final(const ushort* __restrict__ x1, const ushort* __restrict__ x2r,
    const int* __restrict__ cntg, const int* __restrict__ ssrc1, const float* __restrict__ stime1,
    const float* __restrict__ p1, const float* __restrict__ p2,
    const float* __restrict__ Wsg, const float* __restrict__ bsg,
    const float* __restrict__ ntime, const float* __restrict__ Wtg, const float* __restrict__ btg,
    float* __restrict__ out, int N){
  int node = blockIdx.x*4 + (threadIdx.x>>6);
  if (node >= N) return;
  int lane = threadIdx.x & 63;
  int degt = cntg[node];
  int deg = degt > MAXDEG ? MAXDEG : degt;
  float acc = 0.f;
  if (lane < deg){
    size_t o = (size_t)node*MAXDEG + lane;
    float z = p1[ssrc1[o]] + p2[node] + bsg[0] + stime1[o]*Wsg[385];
    acc = 1.f / (1.f + __expf(-z));
  }
  acc = wred_sum(acc);
  float sm = acc / ((float)degt + EPSF);
  float nt = ntime[node];
  int c0 = lane << 2;
  ushort4 au = *(const ushort4*)(x1  + (size_t)node*256 + c0);
  ushort4 ru = *(const ushort4*)(x2r + (size_t)node*256 + c0);
  float4 a4 = make_float4(bf2f(au.x), bf2f(au.y), bf2f(au.z), bf2f(au.w));
  float4 b4; b4.x = bf2f(ru.x)*sm; b4.y = bf2f(ru.y)*sm; b4.z = bf2f(ru.z)*sm; b4.w = bf2f(ru.w)*sm;
  float4 w1 = *(const float4*)(Wtg + c0);
  float4 w2 = *(const float4*)(Wtg + 257 + c0);
  float s = a4.x*w1.x + a4.y*w1.y + a4.z*w1.z + a4.w*w1.w
          + b4.x*w2.x + b4.y*w2.y + b4.z*w2.z + b4.w*w2.w;
  if (lane == 0) s += nt*Wtg[256] + nt*Wtg[513] + btg[0];
  s = wred_sum(s);
  float g = 1.f / (1.f + __expf(-s));
  float* orow = out + (size_t)node*257;
  orow[c0+0] = g*b4.x + (1.f - g)*a4.x;
  orow[c0+1] = g*b4.y + (1.f - g)*a4.y;
  orow[c0+2] = g*b4.z + (1.f - g)*a4.z;
  orow[c0+3] = g*b4.w + (1.f - g)*a4.w;
  if (lane == 0) orow[256] = nt;
}

// ---------------- launch ----------------

extern "C" void kernel_launch(void* const* d_in, const int* in_sizes, int n_in,
                              void* d_out, int out_size, void* d_ws, size_t ws_size,
                              hipStream_t stream){
  const float* x    = (const float*)d_in[0];
  const int*   ei1  = (const int*)d_in[1];
  const float* et1  = (const float*)d_in[2];
  const int*   ei2  = (const int*)d_in[3];
  const float* rel  = (const float*)d_in[5];
  const float* Wg   = (const float*)d_in[6];
  const float* asrc = (const float*)d_in[7];
  const float* adst = (const float*)d_in[8];
  const float* bg   = (const float*)d_in[9];
  const float* Wlin = (const float*)d_in[10];
  const float* blin = (const float*)d_in[11];
  const float* Wtg  = (const float*)d_in[12];
  const float* btg  = (const float*)d_in[13];
  const float* Wsg  = (const float*)d_in[14];
  const float* bsg  = (const float*)d_in[15];
  float* out = (float*)d_out;

  const int N  = in_sizes[0] / 256;
  const int E1 = in_sizes[1] / 2;
  const int E2 = in_sizes[3] / 2;
  const int NB = (N + NBUCK - 1) / NBUCK;
  const int cap1 = E1/NBUCK + 2048;
  const int cap2 = E2/NBUCK + 2048;

  char* base = (char*)d_ws;
  size_t off = 0;
  auto alloc = [&](size_t bytes)->char*{
    char* p = base + off;
    off += (bytes + 255) & ~(size_t)255;
    return p;
  };
  // zeroed region (cleared by k_prep): gcur | as_ | ad_ (accumulated via atomicAdd)
  int*    gcur  = (int*)alloc((size_t)2*NBUCK*4);
  float*  as_   = (float*)alloc((size_t)2*N*4);
  float*  ad_   = (float*)alloc((size_t)2*N*4);
  size_t zero_bytes = off;
  ushort* Wgt   = (ushort*)alloc((size_t)256*256*2);
  ushort* Wlt   = (ushort*)alloc((size_t)256*256*2);
  ushort* xb    = (ushort*)alloc((size_t)N*256*2);
  ushort* hb    = (ushort*)alloc((size_t)N*256*2);
  ushort* gatb  = (ushort*)alloc((size_t)2*N*256*2);
  ushort* x12   = (ushort*)alloc((size_t)2*N*256*2);
  float*  ntime = (float*)alloc((size_t)N*4);
  float*  p1    = (float*)alloc((size_t)N*4);
  float*  p2    = (float*)alloc((size_t)N*4);
  int*    cntg  = (int*)alloc((size_t)2*N*4);
  int*    ssrc1 = (int*)alloc((size_t)N*MAXDEG*4);
  int*    ssrc2 = (int*)alloc((size_t)N*MAXDEG*4);
  float*  stime1= (float*)alloc((size_t)N*MAXDEG*4);
  int2*   bkt1  = (int2*)alloc((size_t)NBUCK*cap1*8);
  int2*   bkt2  = (int2*)alloc((size_t)NBUCK*cap2*8);

  dim3 blk(256);
  int gN4 = (N + 3) / 4;
  int GB1 = ((N + 127) / 128) * 2;
  int B1  = (E1 + BINCH - 1) / BINCH;
  int B2  = (E2 + BINCH - 1) / BINCH;
  int znum4 = (int)(zero_bytes / 16);
  int ZB = (znum4 + 255) / 256;
  int CB = (N*256/8 + 255) / 256;
  dim3 ggemm2((2*N + 127) / 128, 2);

  k_prep<<<ZB + 128 + CB + gN4, blk, 0, stream>>>(Wg, Wlin, rel, Wsg, x, Wgt, Wlt, xb, p2,
                                                  (float4*)d_ws, znum4, ZB, CB, N);
  k_work1<<<GB1 + B1 + B2, blk, 0, stream>>>(xb, Wgt, asrc, adst, hb, as_, ad_,
                                             ei1, et1, ei2, gcur, bkt1, bkt2,
                                             cap1, cap2, N, E1, E2, GB1, B1, NB);
  k_place<<<128, blk, 0, stream>>>(gcur, bkt1, bkt2, cap1, cap2, ssrc1, ssrc2, stime1,
                                   cntg, ntime, p1, Wsg, N, NB);
  k_node<<<2*gN4, blk, 0, stream>>>(cntg, ssrc1, ssrc2, as_, ad_, hb, bg, gatb, N, gN4);
  k_gemm2<<<ggemm2, blk, 0, stream>>>(gatb, Wlt, blin, Wsg, x12, p1, 2*N, N);
  k_final<<<gN4, blk, 0, stream>>>(x12, x12 + (size_t)N*256, cntg, ssrc1, stime1,
                                   p1, p2, Wsg, bsg, ntime, Wtg, btg, out, N);
}